// Round 7
// baseline (824.680 us; speedup 1.0000x reference)
//
#include <hip/hip_runtime.h>

typedef unsigned short u16;
typedef __attribute__((ext_vector_type(8))) short bf16x8;
typedef __attribute__((ext_vector_type(4))) float f32x4;

#define B_      2
#define L_      1024
#define DM      1024
#define DI      2048
#define NH      32
#define HD      64
#define DSTATE  64
#define CONVD   2176
#define DPROJ   4256
#define ZXS     4352   // padded zx row stride (34*128)

__device__ __forceinline__ u16 f2bf(float f) {
  union { float f; unsigned u; } v; v.f = f;
  unsigned r = v.u + 0x7fffu + ((v.u >> 16) & 1u);   // RNE
  return (u16)(r >> 16);
}
__device__ __forceinline__ float bf2f(u16 b) {
  union { unsigned u; float f; } v; v.u = ((unsigned)b) << 16;
  return v.f;
}

__device__ __forceinline__ void load_lds16(const void* g, void* l) {
  __builtin_amdgcn_global_load_lds(
      (const __attribute__((address_space(1))) void*)g,
      (__attribute__((address_space(3))) void*)l, 16, 0, 0);
}

template<int P> __device__ __forceinline__ void wait_prefetch() {
  if constexpr (P == 4)      asm volatile("s_waitcnt vmcnt(4)\n\ts_barrier" ::: "memory");
  else if constexpr (P == 6) asm volatile("s_waitcnt vmcnt(6)\n\ts_barrier" ::: "memory");
  else if constexpr (P == 8) asm volatile("s_waitcnt vmcnt(8)\n\ts_barrier" ::: "memory");
}

__device__ __forceinline__ float block_reduce_sum256(float v) {
  #pragma unroll
  for (int off = 32; off > 0; off >>= 1) v += __shfl_down(v, off, 64);
  __shared__ float red[4];
  int lane = threadIdx.x & 63, w = threadIdx.x >> 6;
  if (lane == 0) red[w] = v;
  __syncthreads();
  return red[0] + red[1] + red[2] + red[3];
}

// ---------------- merged: rmsnorm(x) (blocks 0..2047) + weight convert (rest) ----------------
__global__ __launch_bounds__(256) void rms_and_convert(
    const float* __restrict__ x, const float* __restrict__ norm_w, u16* __restrict__ xlnb,
    const float* __restrict__ W_in, const float* __restrict__ W_out,
    const float* __restrict__ w1, const float* __restrict__ w2,
    u16* __restrict__ Winb, u16* __restrict__ Woutb, u16* __restrict__ w12b) {
  if (blockIdx.x < 2048) {
    const int row = blockIdx.x;
    const int c = threadIdx.x << 2;
    float4 v = *(const float4*)(x + (long)row * DM + c);
    float ss = v.x * v.x + v.y * v.y + v.z * v.z + v.w * v.w;
    float tot = block_reduce_sum256(ss);
    float sc = rsqrtf(tot * (1.0f / DM) + 1e-6f);
    float4 wv = *(const float4*)(norm_w + c);
    *(ushort4*)(xlnb + (long)row * DM + c) =
        make_ushort4(f2bf(v.x * sc * wv.x), f2bf(v.y * sc * wv.y),
                     f2bf(v.z * sc * wv.z), f2bf(v.w * sc * wv.w));
    return;
  }
  const long R0 = 4256L * 1024 / 4;
  const long R1 = R0 + 2048L * 1024 / 4;
  long i = (long)(blockIdx.x - 2048) * 256 + threadIdx.x;
  float4 v;
  ushort4* dst;
  if (i < R0) {
    v = ((const float4*)W_in)[i];
    dst = ((ushort4*)Winb) + i;
  } else if (i < R1) {
    long j = i - R0;
    v = ((const float4*)W_out)[j];
    dst = ((ushort4*)Woutb) + j;
  } else {
    long j = i - R1;
    long row = j >> 8;
    const float* s = (row < 1024) ? (w1 + row * 1024) : (w2 + (row - 1024) * 1024);
    v = ((const float4*)s)[j & 255];
    dst = ((ushort4*)w12b) + j;
  }
  *dst = make_ushort4(f2bf(v.x), f2bf(v.y), f2bf(v.z), f2bf(v.w));
}

// ---------------- rmsnorm of (x + xf) -> bf16 ----------------
__global__ __launch_bounds__(256) void add_rms_kernel(
    const float* __restrict__ in1, const float* __restrict__ in2,
    const float* __restrict__ wt, u16* __restrict__ out, float eps) {
  const int row = blockIdx.x;
  const int c = threadIdx.x << 2;
  float4 v = *(const float4*)(in1 + (long)row * DM + c);
  float4 u = *(const float4*)(in2 + (long)row * DM + c);
  v.x += u.x; v.y += u.y; v.z += u.z; v.w += u.w;
  float ss = v.x * v.x + v.y * v.y + v.z * v.z + v.w * v.w;
  float tot = block_reduce_sum256(ss);
  float sc = rsqrtf(tot * (1.0f / DM) + eps);
  float4 wv = *(const float4*)(wt + c);
  *(ushort4*)(out + (long)row * DM + c) =
      make_ushort4(f2bf(v.x * sc * wv.x), f2bf(v.y * sc * wv.y),
                   f2bf(v.z * sc * wv.z), f2bf(v.w * sc * wv.w));
}

// ============ bf16 NT GEMM: tile (NI*32)x(NJ*32), dbuf LDS + vmcnt prefetch ============
// OUT: 0 = f32 store, 1 = bf16 store, 2 = f32 atomicAdd (split-K).
template<int NI, int NJ, int OUT>
__global__ __launch_bounds__(256) void gemm_lds(
    const u16* __restrict__ A, const u16* __restrict__ Bw,
    void* __restrict__ Cv, int N, int Nw, int Ksub, int Kstride) {
  constexpr int BM = NI * 32;
  constexpr int BN = NJ * 32;
  __shared__ u16 As[2][BM][64];
  __shared__ u16 Bs[2][BN][64];
  const int tid = threadIdx.x;
  const int lane = tid & 63;
  const int wave = tid >> 6;
  const int ml = lane & 15;
  const int quad = lane >> 4;
  const int wm = (wave & 1) * (NI * 16);
  const int wn = (wave >> 1) * (NJ * 16);
  const long bm = (long)blockIdx.y * BM;
  const long bn = (long)blockIdx.x * BN;
  const long koff = (long)blockIdx.z * Ksub;

  const int lr = lane >> 3;
  const int lc = (lane & 7) ^ lr;

  f32x4 acc[NI][NJ];
  #pragma unroll
  for (int i = 0; i < NI; ++i)
    #pragma unroll
    for (int j = 0; j < NJ; ++j)
      acc[i][j] = (f32x4){0.f, 0.f, 0.f, 0.f};

  auto stage = [&](int kk, int buf) {
    #pragma unroll
    for (int t = 0; t < BM / 32; ++t) {
      const int u = wave * (BM / 32) + t;
      load_lds16(A + (bm + u * 8 + lr) * Kstride + koff + kk + lc * 8, &As[buf][u * 8][0]);
    }
    #pragma unroll
    for (int t = 0; t < BN / 32; ++t) {
      const int u = wave * (BN / 32) + t;
      long brow = bn + u * 8 + lr;
      if (brow >= Nw) brow = Nw - 1;
      load_lds16(Bw + brow * Kstride + koff + kk + lc * 8, &Bs[buf][u * 8][0]);
    }
  };

  stage(0, 0);
  int buf = 0;
  for (int kt = 0; kt < Ksub; kt += 64) {
    if (kt + 64 < Ksub) {
      stage(kt + 64, buf ^ 1);
      wait_prefetch<NI + NJ>();
    } else {
      asm volatile("s_waitcnt vmcnt(0)\n\ts_barrier" ::: "memory");
    }
    #pragma unroll
    for (int ks = 0; ks < 2; ++ks) {
      const int c = ks * 4 + quad;
      const int pc = (c ^ (ml & 7)) << 3;
      bf16x8 af[NI], bfr[NJ];
      #pragma unroll
      for (int i = 0; i < NI; ++i)
        af[i] = *(const bf16x8*)&As[buf][wm + (i << 4) + ml][pc];
      #pragma unroll
      for (int j = 0; j < NJ; ++j)
        bfr[j] = *(const bf16x8*)&Bs[buf][wn + (j << 4) + ml][pc];
      #pragma unroll
      for (int i = 0; i < NI; ++i)
        #pragma unroll
        for (int j = 0; j < NJ; ++j)
          acc[i][j] = __builtin_amdgcn_mfma_f32_16x16x32_bf16(af[i], bfr[j], acc[i][j], 0, 0, 0);
    }
    asm volatile("s_barrier" ::: "memory");   // LDS WAR vs next iter's stage
    buf ^= 1;
  }

  const int rquad = quad << 2;
  #pragma unroll
  for (int i = 0; i < NI; ++i) {
    const long gm = bm + wm + (i << 4) + rquad;
    #pragma unroll
    for (int j = 0; j < NJ; ++j) {
      const long gn = bn + wn + (j << 4) + ml;
      #pragma unroll
      for (int r = 0; r < 4; ++r) {
        if constexpr (OUT == 0)
          ((float*)Cv)[(gm + r) * N + gn] = acc[i][j][r];
        else if constexpr (OUT == 1)
          ((u16*)Cv)[(gm + r) * N + gn] = f2bf(acc[i][j][r]);
        else
          atomicAdd(&((float*)Cv)[(gm + r) * N + gn], acc[i][j][r]);
      }
    }
  }
}

// ============ fused MLP GEMM + silu-gate + both outputs (g/h split tile) ============
__global__ __launch_bounds__(256) void gemm_mlp_final(
    const u16* __restrict__ A, const u16* __restrict__ Bw,
    const float* __restrict__ x0, const float* __restrict__ xd,
    const float* __restrict__ xf, float* __restrict__ out, int K) {
  __shared__ u16 As[2][64][64];
  __shared__ u16 Bs[2][128][64];
  const int tid = threadIdx.x;
  const int lane = tid & 63;
  const int wave = tid >> 6;
  const int ml = lane & 15;
  const int quad = lane >> 4;
  const int wm = (wave & 1) * 32;
  const int wn = (wave >> 1) * 32;
  const long bm = (long)blockIdx.y * 64;
  const long c0 = (long)blockIdx.x * 64;

  const int lr = lane >> 3;
  const int lc = (lane & 7) ^ lr;

  f32x4 acc[2][4];
  #pragma unroll
  for (int i = 0; i < 2; ++i)
    #pragma unroll
    for (int j = 0; j < 4; ++j)
      acc[i][j] = (f32x4){0.f, 0.f, 0.f, 0.f};

  auto stage = [&](int kk, int buf) {
    #pragma unroll
    for (int t = 0; t < 2; ++t) {
      const int u = wave * 2 + t;
      load_lds16(A + (bm + u * 8 + lr) * K + kk + lc * 8, &As[buf][u * 8][0]);
    }
    #pragma unroll
    for (int t = 0; t < 4; ++t) {
      const int u = wave * 4 + t;
      const int r = u * 8 + lr;
      const long grow = (r < 64) ? (c0 + r) : (1024 + c0 + (r - 64));
      load_lds16(Bw + grow * K + kk + lc * 8, &Bs[buf][u * 8][0]);
    }
  };

  stage(0, 0);
  int buf = 0;
  for (int kt = 0; kt < K; kt += 64) {
    if (kt + 64 < K) {
      stage(kt + 64, buf ^ 1);
      wait_prefetch<6>();
    } else {
      asm volatile("s_waitcnt vmcnt(0)\n\ts_barrier" ::: "memory");
    }
    #pragma unroll
    for (int ks = 0; ks < 2; ++ks) {
      const int c = ks * 4 + quad;
      const int pc = (c ^ (ml & 7)) << 3;
      bf16x8 af[2], bfr[4];
      #pragma unroll
      for (int i = 0; i < 2; ++i)
        af[i] = *(const bf16x8*)&As[buf][wm + (i << 4) + ml][pc];
      #pragma unroll
      for (int j = 0; j < 2; ++j) {
        bfr[j]     = *(const bf16x8*)&Bs[buf][wn + (j << 4) + ml][pc];
        bfr[j + 2] = *(const bf16x8*)&Bs[buf][64 + wn + (j << 4) + ml][pc];
      }
      #pragma unroll
      for (int i = 0; i < 2; ++i)
        #pragma unroll
        for (int j = 0; j < 4; ++j)
          acc[i][j] = __builtin_amdgcn_mfma_f32_16x16x32_bf16(af[i], bfr[j], acc[i][j], 0, 0, 0);
    }
    asm volatile("s_barrier" ::: "memory");
    buf ^= 1;
  }

  float* out1 = out + (long)B_ * L_ * DM;
  const int rquad = quad << 2;
  #pragma unroll
  for (int i = 0; i < 2; ++i) {
    const long gm = bm + wm + (i << 4) + rquad;
    #pragma unroll
    for (int jj = 0; jj < 2; ++jj) {
      const long col = c0 + wn + (jj << 4) + ml;
      #pragma unroll
      for (int r = 0; r < 4; ++r) {
        float g = acc[i][jj][r];
        float h = acc[i][jj + 2][r];
        float e = (g / (1.f + expf(-g))) * h;
        long o = (gm + r) * DM + col;
        float f = xf[o];
        out[o]  = x0[o] + f + e;
        out1[o] = xd[o] + f + e;
      }
    }
  }
}

// ================= FUSED SSD: conv+silu, chunk GEMMs, chained carry, inter-chunk =================
// One block per (b,h,c) assigned by ticket (guarantees predecessors started first).
// Chain: H_out = lam_c * H_in + S_c, passed via device-scope atomics in carry[].
__global__ __launch_bounds__(256) void ssd_fused_kernel(
    const u16* __restrict__ zx, const float* __restrict__ dt_bias,
    const float* __restrict__ A_log, const float* __restrict__ cw,
    const float* __restrict__ cb, const float* __restrict__ Dp,
    u16* __restrict__ yss, float* __restrict__ carry,
    int* __restrict__ flags, int* __restrict__ ticket) {
  __shared__ u16 Cs[64][72], Bs[64][72], Xt[64][72], Btw[64][72], Ms[64][72];
  __shared__ float Gs[64], wjL[64], dtL[64], egL[64];
  __shared__ int tickL;
  const int tid = threadIdx.x, lane = tid & 63, wave = tid >> 6;

  if (tid == 0) tickL = atomicAdd(ticket, 1);
  __syncthreads();
  const int tick = tickL;
  const int c = tick & 15;
  const int h = (tick >> 4) & 31;
  const int b = tick >> 9;
  const int bh = b * NH + h;
  const long zrow0 = (long)b * L_;      // zx row base for this batch
  const long crow = zrow0 + c * 64;     // chunk row base

  // --- wave0: dt, log-decay prefix, per-chunk scalars ---
  if (wave == 0) {
    float draw = bf2f(zx[(crow + lane) * ZXS + (DI + CONVD) + h]) + dt_bias[h];
    float dt = (draw > 20.f) ? draw : log1pf(expf(draw));
    float g = -expf(A_log[h]) * dt;
    float G = g;
    #pragma unroll
    for (int off = 1; off < 64; off <<= 1) {
      float t = __shfl_up(G, off, 64);
      if (lane >= off) G += t;
    }
    float G63 = __shfl(G, 63, 64);
    Gs[lane] = G;
    egL[lane] = expf(G);
    wjL[lane] = expf(G63 - G) * dt;
    dtL[lane] = dt;
  }
  __syncthreads();

  // --- staging with fused conv+silu from zx (x-slice, B, C) ---
  for (int idx = tid; idx < 3072; idx += 256) {
    int r = idx / 48;          // chunk-local time 0..63
    int g = idx % 48;          // col group (x:0-15, B:16-31, C:32-47)
    int t = c * 64 + r;        // sequence time
    long zcol;
    if (g < 16)      zcol = DI + (long)h * HD + (g << 2);
    else if (g < 32) zcol = DI + DI + ((g - 16) << 2);
    else             zcol = DI + DI + DSTATE + ((g - 32) << 2);
    int cc = (int)(zcol - DI);   // conv channel
    float4 acc = *(const float4*)(cb + cc);
    float4 wv0 = *(const float4*)(cw + (cc + 0) * 4);
    float4 wv1 = *(const float4*)(cw + (cc + 1) * 4);
    float4 wv2 = *(const float4*)(cw + (cc + 2) * 4);
    float4 wv3 = *(const float4*)(cw + (cc + 3) * 4);
    const float wt0[4] = {wv0.x, wv0.y, wv0.z, wv0.w};
    const float wt1[4] = {wv1.x, wv1.y, wv1.z, wv1.w};
    const float wt2[4] = {wv2.x, wv2.y, wv2.z, wv2.w};
    const float wt3[4] = {wv3.x, wv3.y, wv3.z, wv3.w};
    #pragma unroll
    for (int i = 0; i < 4; ++i) {
      int tau = t - 3 + i;
      if (tau >= 0) {
        ushort4 xb = *(const ushort4*)(zx + (zrow0 + tau) * ZXS + zcol);
        acc.x = fmaf(bf2f(xb.x), wt0[i], acc.x);
        acc.y = fmaf(bf2f(xb.y), wt1[i], acc.y);
        acc.z = fmaf(bf2f(xb.z), wt2[i], acc.z);
        acc.w = fmaf(bf2f(xb.w), wt3[i], acc.w);
      }
    }
    acc.x = acc.x / (1.f + expf(-acc.x));
    acc.y = acc.y / (1.f + expf(-acc.y));
    acc.z = acc.z / (1.f + expf(-acc.z));
    acc.w = acc.w / (1.f + expf(-acc.w));
    if (g < 16) {               // x -> Xt transposed [p][time]
      int k = g << 2;
      Xt[k + 0][r] = f2bf(acc.x); Xt[k + 1][r] = f2bf(acc.y);
      Xt[k + 2][r] = f2bf(acc.z); Xt[k + 3][r] = f2bf(acc.w);
    } else if (g < 32) {        // B -> Bs [time][n], Btw transposed*w [n][time]
      int n = (g - 16) << 2;
      *(ushort4*)&Bs[r][n] = make_ushort4(f2bf(acc.x), f2bf(acc.y), f2bf(acc.z), f2bf(acc.w));
      float w = wjL[r];
      Btw[n + 0][r] = f2bf(acc.x * w); Btw[n + 1][r] = f2bf(acc.y * w);
      Btw[n + 2][r] = f2bf(acc.z * w); Btw[n + 3][r] = f2bf(acc.w * w);
    } else {                    // C -> Cs [time][n]
      int n = (g - 32) << 2;
      *(ushort4*)&Cs[r][n] = make_ushort4(f2bf(acc.x), f2bf(acc.y), f2bf(acc.z), f2bf(acc.w));
    }
  }
  __syncthreads();

  const int ml = lane & 15;
  const int mrow = wave * 16 + ml;
  const int quad = lane >> 4;
  // --- GEMM1: E = C.B^T ---
  f32x4 accE[4];
  #pragma unroll
  for (int j = 0; j < 4; ++j) accE[j] = (f32x4){0.f, 0.f, 0.f, 0.f};
  #pragma unroll
  for (int ks = 0; ks < 2; ++ks) {
    int k0 = ks * 32 + quad * 8;
    bf16x8 a = *(const bf16x8*)&Cs[mrow][k0];
    #pragma unroll
    for (int j = 0; j < 4; ++j) {
      bf16x8 bfr = *(const bf16x8*)&Bs[j * 16 + ml][k0];
      accE[j] = __builtin_amdgcn_mfma_f32_16x16x32_bf16(a, bfr, accE[j], 0, 0, 0);
    }
  }
  // mask + scale -> Ms (bf16)
  #pragma unroll
  for (int j = 0; j < 4; ++j) {
    int jc = j * 16 + ml;
    float Gj = Gs[jc], dtj = dtL[jc];
    #pragma unroll
    for (int r = 0; r < 4; ++r) {
      int ir = wave * 16 + quad * 4 + r;
      float v = (ir >= jc) ? accE[j][r] * expf(Gs[ir] - Gj) * dtj : 0.f;
      Ms[ir][jc] = f2bf(v);
    }
  }
  __syncthreads();
  // --- GEMM2: Y_intra = M.X ; GEMM3: S^T = X^T.(Bw)^T ---
  f32x4 accY[4], accS[4];
  #pragma unroll
  for (int j = 0; j < 4; ++j) { accY[j] = (f32x4){0.f,0.f,0.f,0.f}; accS[j] = (f32x4){0.f,0.f,0.f,0.f}; }
  #pragma unroll
  for (int ks = 0; ks < 2; ++ks) {
    int k0 = ks * 32 + quad * 8;
    bf16x8 aM = *(const bf16x8*)&Ms[mrow][k0];
    bf16x8 aX = *(const bf16x8*)&Xt[mrow][k0];
    #pragma unroll
    for (int j = 0; j < 4; ++j) {
      bf16x8 bX = *(const bf16x8*)&Xt[j * 16 + ml][k0];
      bf16x8 bB = *(const bf16x8*)&Btw[j * 16 + ml][k0];
      accY[j] = __builtin_amdgcn_mfma_f32_16x16x32_bf16(aM, bX, accY[j], 0, 0, 0);
      accS[j] = __builtin_amdgcn_mfma_f32_16x16x32_bf16(aX, bB, accS[j], 0, 0, 0);
    }
  }

  // --- chained carry: H_out = lam*H_in + S ---
  const float lam = egL[63];
  float* myslot = carry + (long)(bh * 16 + c) * 4096;
  float Hin[4][4];
  if (c > 0) {
    float* prev = carry + (long)(bh * 16 + c - 1) * 4096;
    int* fl = flags + bh * 16 + (c - 1);
    if (tid == 0) {
      while (__hip_atomic_load(fl, __ATOMIC_ACQUIRE, __HIP_MEMORY_SCOPE_AGENT) == 0)
        __builtin_amdgcn_s_sleep(2);
    }
    __syncthreads();
    #pragma unroll
    for (int j = 0; j < 4; ++j) {
      int n = j * 16 + ml;
      #pragma unroll
      for (int r = 0; r < 4; ++r) {
        int p = wave * 16 + quad * 4 + r;
        Hin[j][r] = __hip_atomic_load(prev + p * 64 + n, __ATOMIC_RELAXED, __HIP_MEMORY_SCOPE_AGENT);
      }
    }
  } else {
    #pragma unroll
    for (int j = 0; j < 4; ++j)
      #pragma unroll
      for (int r = 0; r < 4; ++r) Hin[j][r] = 0.f;
  }
  // publish H_out ASAP
  #pragma unroll
  for (int j = 0; j < 4; ++j) {
    int n = j * 16 + ml;
    #pragma unroll
    for (int r = 0; r < 4; ++r) {
      int p = wave * 16 + quad * 4 + r;
      float hout = fmaf(lam, Hin[j][r], accS[j][r]);
      __hip_atomic_store(myslot + p * 64 + n, hout, __ATOMIC_RELAXED, __HIP_MEMORY_SCOPE_AGENT);
    }
  }
  __threadfence();
  __syncthreads();   // all stores fenced; also: Ms reads (GEMM2) done -> safe to reuse
  if (tid == 0)
    __hip_atomic_store(flags + bh * 16 + c, 1, __ATOMIC_RELEASE, __HIP_MEMORY_SCOPE_AGENT);

  // --- inter-chunk: Y_inter = C . H_in^T (then scaled by exp(G_i)) ---
  f32x4 accI[4];
  #pragma unroll
  for (int j = 0; j < 4; ++j) accI[j] = (f32x4){0.f, 0.f, 0.f, 0.f};
  if (c > 0) {
    #pragma unroll
    for (int j = 0; j < 4; ++j) {      // Hin (bf16) into Ms as [p][n]
      int n = j * 16 + ml;
      #pragma unroll
      for (int r = 0; r < 4; ++r) {
        int p = wave * 16 + quad * 4 + r;
        Ms[p][n] = f2bf(Hin[j][r]);
      }
    }
    __syncthreads();
    #pragma unroll
    for (int ks = 0; ks < 2; ++ks) {
      int k0 = ks * 32 + quad * 8;
      bf16x8 a = *(const bf16x8*)&Cs[mrow][k0];
      #pragma unroll
      for (int j = 0; j < 4; ++j) {
        bf16x8 bfr = *(const bf16x8*)&Ms[j * 16 + ml][k0];
        accI[j] = __builtin_amdgcn_mfma_f32_16x16x32_bf16(a, bfr, accI[j], 0, 0, 0);
      }
    }
  }

  // --- final write: y = Y_intra + eg*Y_inter + D*x ---
  const float Dh = Dp[h];
  #pragma unroll
  for (int j = 0; j < 4; ++j) {
    int p = j * 16 + ml;
    #pragma unroll
    for (int r = 0; r < 4; ++r) {
      int i = wave * 16 + quad * 4 + r;
      float xval = bf2f(Xt[p][i]);
      float y = accY[j][r] + egL[i] * accI[j][r] + Dh * xval;
      yss[(crow + i) * DI + (long)h * HD + p] = f2bf(y);
    }
  }
}

// ---------------- gated rmsnorm (bf16 y,z) + zero xf for split-K atomics ----------------
__global__ __launch_bounds__(256) void gated_rms_kernel(
    const u16* __restrict__ y, const u16* __restrict__ zx,
    const float* __restrict__ wt, u16* __restrict__ out,
    float* __restrict__ xf_zero) {
  const int row = blockIdx.x;
  const int c = threadIdx.x << 3;
  const u16* yr = y + (long)row * DI + c;
  const u16* zr = zx + (long)row * ZXS + c;
  *(float4*)(xf_zero + (long)row * DM + (threadIdx.x << 2)) = make_float4(0.f, 0.f, 0.f, 0.f);
  float v[8];
  float ss = 0.f;
  #pragma unroll
  for (int i = 0; i < 8; i += 4) {
    ushort4 y4 = *(const ushort4*)(yr + i);
    ushort4 z4 = *(const ushort4*)(zr + i);
    const float zz[4] = {bf2f(z4.x), bf2f(z4.y), bf2f(z4.z), bf2f(z4.w)};
    const float yy[4] = {bf2f(y4.x), bf2f(y4.y), bf2f(y4.z), bf2f(y4.w)};
    #pragma unroll
    for (int j = 0; j < 4; ++j) {
      float sg = zz[j] / (1.f + expf(-zz[j]));
      float val = yy[j] * sg;
      v[i + j] = val;
      ss += val * val;
    }
  }
  float tot = block_reduce_sum256(ss);
  float sc = rsqrtf(tot * (1.0f / DI) + 1e-5f);
  const float* wr = wt + c;
  *(ushort4*)(out + (long)row * DI + c) =
      make_ushort4(f2bf(v[0] * sc * wr[0]), f2bf(v[1] * sc * wr[1]),
                   f2bf(v[2] * sc * wr[2]), f2bf(v[3] * sc * wr[3]));
  *(ushort4*)(out + (long)row * DI + c + 4) =
      make_ushort4(f2bf(v[4] * sc * wr[4]), f2bf(v[5] * sc * wr[5]),
                   f2bf(v[6] * sc * wr[6]), f2bf(v[7] * sc * wr[7]));
}

extern "C" void kernel_launch(void* const* d_in, const int* in_sizes, int n_in,
                              void* d_out, int out_size, void* d_ws, size_t ws_size,
                              hipStream_t stream) {
  const float* x        = (const float*)d_in[0];
  const float* x_d      = (const float*)d_in[1];
  const float* norm_w   = (const float*)d_in[2];
  const float* W_in     = (const float*)d_in[3];
  const float* conv_w   = (const float*)d_in[4];
  const float* conv_b   = (const float*)d_in[5];
  const float* dt_bias  = (const float*)d_in[6];
  const float* A_log    = (const float*)d_in[7];
  const float* D_param  = (const float*)d_in[8];
  const float* ssm_w    = (const float*)d_in[9];
  const float* W_out    = (const float*)d_in[10];
  const float* w1       = (const float*)d_in[11];
  const float* w2       = (const float*)d_in[12];
  float* out = (float*)d_out;

  char* wsc = (char*)d_ws;
  size_t off = 0;
  auto alloc = [&](size_t n) { char* p = wsc + off; off += (n + 255) & ~(size_t)255; return p; };
  u16*   zx   = (u16*)alloc((size_t)2048 * ZXS * 2);
  u16*   yss  = (u16*)alloc((size_t)2048 * 2048 * 2);
  float* xf   = (float*)alloc((size_t)2048 * 1024 * 4);
  float* carry= (float*)alloc((size_t)64 * 16 * 4096 * 4);
  int*   flags= (int*)alloc((size_t)1028 * 4);          // 1024 flags + ticket
  u16* xlnb   = (u16*)alloc((size_t)2048 * 1024 * 2);
  u16* ygnb   = (u16*)alloc((size_t)2048 * 2048 * 2);
  u16* xln2b  = (u16*)alloc((size_t)2048 * 1024 * 2);
  u16* Winb   = (u16*)alloc((size_t)4256 * 1024 * 2);
  u16* Woutb  = (u16*)alloc((size_t)1024 * 2048 * 2);
  u16* w12b   = (u16*)alloc((size_t)2048 * 1024 * 2);
  int* ticket = flags + 1024;

  // flags + ticket must be zero every launch (ws is re-poisoned)
  hipMemsetAsync(flags, 0, 1028 * 4, stream);
  // 0+1) rmsnorm(x) + all weight conversions, one launch
  rms_and_convert<<<2048 + 8352, 256, 0, stream>>>(x, norm_w, xlnb,
      W_in, W_out, w1, w2, Winb, Woutb, w12b);
  // 2) in-proj -> bf16 zx (padded stride)
  gemm_lds<4, 2, 1><<<dim3(68, 16), 256, 0, stream>>>(xlnb, Winb, zx, ZXS, 4256, 1024, 1024);
  // 3) fused SSD (conv + chunk + chained carry + inter-chunk + D*x)
  ssd_fused_kernel<<<1024, 256, 0, stream>>>(zx, dt_bias, A_log, conv_w, conv_b,
                                             D_param, yss, carry, flags, ticket);
  // 4) gated rmsnorm -> bf16 (+ zeroes xf for split-K)
  gated_rms_kernel<<<2048, 256, 0, stream>>>(yss, zx, ssm_w, ygnb, xf);
  // 5) out-proj: split-K=2, atomicAdd into xf
  gemm_lds<2, 2, 2><<<dim3(16, 32, 2), 256, 0, stream>>>(ygnb, Woutb, xf, 1024, 1024, 1024, 2048);
  // 6) rmsnorm(x + xf) -> bf16
  add_rms_kernel<<<2048, 256, 0, stream>>>(x, xf, norm_w, xln2b, 1e-6f);
  // 7) fused MLP GEMM + gate + final outputs
  gemm_mlp_final<<<dim3(16, 32), 256, 0, stream>>>(xln2b, w12b, x, x_d, xf, out, 1024);
}

// Round 9
// 292.657 us; speedup vs baseline: 2.8179x; 2.8179x over previous
//
#include <hip/hip_runtime.h>

typedef unsigned short u16;
typedef __attribute__((ext_vector_type(8))) short bf16x8;
typedef __attribute__((ext_vector_type(4))) float f32x4;

#define B_      2
#define L_      1024
#define DM      1024
#define DI      2048
#define NH      32
#define HD      64
#define DSTATE  64
#define CONVD   2176
#define DPROJ   4256
#define ZXS     4352   // padded zx row stride (34*128)

__device__ __forceinline__ u16 f2bf(float f) {
  union { float f; unsigned u; } v; v.f = f;
  unsigned r = v.u + 0x7fffu + ((v.u >> 16) & 1u);   // RNE
  return (u16)(r >> 16);
}
__device__ __forceinline__ float bf2f(u16 b) {
  union { unsigned u; float f; } v; v.u = ((unsigned)b) << 16;
  return v.f;
}

__device__ __forceinline__ void load_lds16(const void* g, void* l) {
  __builtin_amdgcn_global_load_lds(
      (const __attribute__((address_space(1))) void*)g,
      (__attribute__((address_space(3))) void*)l, 16, 0, 0);
}

template<int P> __device__ __forceinline__ void wait_prefetch() {
  if constexpr (P == 4)      asm volatile("s_waitcnt vmcnt(4)\n\ts_barrier" ::: "memory");
  else if constexpr (P == 6) asm volatile("s_waitcnt vmcnt(6)\n\ts_barrier" ::: "memory");
  else if constexpr (P == 8) asm volatile("s_waitcnt vmcnt(8)\n\ts_barrier" ::: "memory");
}

__device__ __forceinline__ float block_reduce_sum256(float v) {
  #pragma unroll
  for (int off = 32; off > 0; off >>= 1) v += __shfl_down(v, off, 64);
  __shared__ float red[4];
  int lane = threadIdx.x & 63, w = threadIdx.x >> 6;
  if (lane == 0) red[w] = v;
  __syncthreads();
  return red[0] + red[1] + red[2] + red[3];
}

// ---------------- merged: rmsnorm(x) (blocks 0..2047) + weight convert (rest) ----------------
__global__ __launch_bounds__(256) void rms_and_convert(
    const float* __restrict__ x, const float* __restrict__ norm_w, u16* __restrict__ xlnb,
    const float* __restrict__ W_in, const float* __restrict__ W_out,
    const float* __restrict__ w1, const float* __restrict__ w2,
    u16* __restrict__ Winb, u16* __restrict__ Woutb, u16* __restrict__ w12b) {
  if (blockIdx.x < 2048) {
    const int row = blockIdx.x;
    const int c = threadIdx.x << 2;
    float4 v = *(const float4*)(x + (long)row * DM + c);
    float ss = v.x * v.x + v.y * v.y + v.z * v.z + v.w * v.w;
    float tot = block_reduce_sum256(ss);
    float sc = rsqrtf(tot * (1.0f / DM) + 1e-6f);
    float4 wv = *(const float4*)(norm_w + c);
    *(ushort4*)(xlnb + (long)row * DM + c) =
        make_ushort4(f2bf(v.x * sc * wv.x), f2bf(v.y * sc * wv.y),
                     f2bf(v.z * sc * wv.z), f2bf(v.w * sc * wv.w));
    return;
  }
  const long R0 = 4256L * 1024 / 4;
  const long R1 = R0 + 2048L * 1024 / 4;
  long i = (long)(blockIdx.x - 2048) * 256 + threadIdx.x;
  float4 v;
  ushort4* dst;
  if (i < R0) {
    v = ((const float4*)W_in)[i];
    dst = ((ushort4*)Winb) + i;
  } else if (i < R1) {
    long j = i - R0;
    v = ((const float4*)W_out)[j];
    dst = ((ushort4*)Woutb) + j;
  } else {
    long j = i - R1;
    long row = j >> 8;
    const float* s = (row < 1024) ? (w1 + row * 1024) : (w2 + (row - 1024) * 1024);
    v = ((const float4*)s)[j & 255];
    dst = ((ushort4*)w12b) + j;
  }
  *dst = make_ushort4(f2bf(v.x), f2bf(v.y), f2bf(v.z), f2bf(v.w));
}

// ---------------- rmsnorm of (x + xf) -> bf16 ----------------
__global__ __launch_bounds__(256) void add_rms_kernel(
    const float* __restrict__ in1, const float* __restrict__ in2,
    const float* __restrict__ wt, u16* __restrict__ out, float eps) {
  const int row = blockIdx.x;
  const int c = threadIdx.x << 2;
  float4 v = *(const float4*)(in1 + (long)row * DM + c);
  float4 u = *(const float4*)(in2 + (long)row * DM + c);
  v.x += u.x; v.y += u.y; v.z += u.z; v.w += u.w;
  float ss = v.x * v.x + v.y * v.y + v.z * v.z + v.w * v.w;
  float tot = block_reduce_sum256(ss);
  float sc = rsqrtf(tot * (1.0f / DM) + eps);
  float4 wv = *(const float4*)(wt + c);
  *(ushort4*)(out + (long)row * DM + c) =
      make_ushort4(f2bf(v.x * sc * wv.x), f2bf(v.y * sc * wv.y),
                   f2bf(v.z * sc * wv.z), f2bf(v.w * sc * wv.w));
}

// ============ bf16 NT GEMM: tile (NI*32)x(NJ*32), dbuf LDS + vmcnt prefetch ============
// OUT: 0 = f32 store, 1 = bf16 store, 2 = f32 atomicAdd (split-K).
template<int NI, int NJ, int OUT>
__global__ __launch_bounds__(256) void gemm_lds(
    const u16* __restrict__ A, const u16* __restrict__ Bw,
    void* __restrict__ Cv, int N, int Nw, int Ksub, int Kstride) {
  constexpr int BM = NI * 32;
  constexpr int BN = NJ * 32;
  __shared__ u16 As[2][BM][64];
  __shared__ u16 Bs[2][BN][64];
  const int tid = threadIdx.x;
  const int lane = tid & 63;
  const int wave = tid >> 6;
  const int ml = lane & 15;
  const int quad = lane >> 4;
  const int wm = (wave & 1) * (NI * 16);
  const int wn = (wave >> 1) * (NJ * 16);
  const long bm = (long)blockIdx.y * BM;
  const long bn = (long)blockIdx.x * BN;
  const long koff = (long)blockIdx.z * Ksub;

  const int lr = lane >> 3;
  const int lc = (lane & 7) ^ lr;

  f32x4 acc[NI][NJ];
  #pragma unroll
  for (int i = 0; i < NI; ++i)
    #pragma unroll
    for (int j = 0; j < NJ; ++j)
      acc[i][j] = (f32x4){0.f, 0.f, 0.f, 0.f};

  auto stage = [&](int kk, int buf) {
    #pragma unroll
    for (int t = 0; t < BM / 32; ++t) {
      const int u = wave * (BM / 32) + t;
      load_lds16(A + (bm + u * 8 + lr) * Kstride + koff + kk + lc * 8, &As[buf][u * 8][0]);
    }
    #pragma unroll
    for (int t = 0; t < BN / 32; ++t) {
      const int u = wave * (BN / 32) + t;
      long brow = bn + u * 8 + lr;
      if (brow >= Nw) brow = Nw - 1;
      load_lds16(Bw + brow * Kstride + koff + kk + lc * 8, &Bs[buf][u * 8][0]);
    }
  };

  stage(0, 0);
  int buf = 0;
  for (int kt = 0; kt < Ksub; kt += 64) {
    if (kt + 64 < Ksub) {
      stage(kt + 64, buf ^ 1);
      wait_prefetch<NI + NJ>();
    } else {
      asm volatile("s_waitcnt vmcnt(0)\n\ts_barrier" ::: "memory");
    }
    #pragma unroll
    for (int ks = 0; ks < 2; ++ks) {
      const int c = ks * 4 + quad;
      const int pc = (c ^ (ml & 7)) << 3;
      bf16x8 af[NI], bfr[NJ];
      #pragma unroll
      for (int i = 0; i < NI; ++i)
        af[i] = *(const bf16x8*)&As[buf][wm + (i << 4) + ml][pc];
      #pragma unroll
      for (int j = 0; j < NJ; ++j)
        bfr[j] = *(const bf16x8*)&Bs[buf][wn + (j << 4) + ml][pc];
      #pragma unroll
      for (int i = 0; i < NI; ++i)
        #pragma unroll
        for (int j = 0; j < NJ; ++j)
          acc[i][j] = __builtin_amdgcn_mfma_f32_16x16x32_bf16(af[i], bfr[j], acc[i][j], 0, 0, 0);
    }
    asm volatile("s_barrier" ::: "memory");   // LDS WAR vs next iter's stage
    buf ^= 1;
  }

  const int rquad = quad << 2;
  #pragma unroll
  for (int i = 0; i < NI; ++i) {
    const long gm = bm + wm + (i << 4) + rquad;
    #pragma unroll
    for (int j = 0; j < NJ; ++j) {
      const long gn = bn + wn + (j << 4) + ml;
      #pragma unroll
      for (int r = 0; r < 4; ++r) {
        if constexpr (OUT == 0)
          ((float*)Cv)[(gm + r) * N + gn] = acc[i][j][r];
        else if constexpr (OUT == 1)
          ((u16*)Cv)[(gm + r) * N + gn] = f2bf(acc[i][j][r]);
        else
          atomicAdd(&((float*)Cv)[(gm + r) * N + gn], acc[i][j][r]);
      }
    }
  }
}

// ============ fused MLP GEMM + silu-gate + both outputs (g/h split tile) ============
__global__ __launch_bounds__(256) void gemm_mlp_final(
    const u16* __restrict__ A, const u16* __restrict__ Bw,
    const float* __restrict__ x0, const float* __restrict__ xd,
    const float* __restrict__ xf, float* __restrict__ out, int K) {
  __shared__ u16 As[2][64][64];
  __shared__ u16 Bs[2][128][64];
  const int tid = threadIdx.x;
  const int lane = tid & 63;
  const int wave = tid >> 6;
  const int ml = lane & 15;
  const int quad = lane >> 4;
  const int wm = (wave & 1) * 32;
  const int wn = (wave >> 1) * 32;
  const long bm = (long)blockIdx.y * 64;
  const long c0 = (long)blockIdx.x * 64;

  const int lr = lane >> 3;
  const int lc = (lane & 7) ^ lr;

  f32x4 acc[2][4];
  #pragma unroll
  for (int i = 0; i < 2; ++i)
    #pragma unroll
    for (int j = 0; j < 4; ++j)
      acc[i][j] = (f32x4){0.f, 0.f, 0.f, 0.f};

  auto stage = [&](int kk, int buf) {
    #pragma unroll
    for (int t = 0; t < 2; ++t) {
      const int u = wave * 2 + t;
      load_lds16(A + (bm + u * 8 + lr) * K + kk + lc * 8, &As[buf][u * 8][0]);
    }
    #pragma unroll
    for (int t = 0; t < 4; ++t) {
      const int u = wave * 4 + t;
      const int r = u * 8 + lr;
      const long grow = (r < 64) ? (c0 + r) : (1024 + c0 + (r - 64));
      load_lds16(Bw + grow * K + kk + lc * 8, &Bs[buf][u * 8][0]);
    }
  };

  stage(0, 0);
  int buf = 0;
  for (int kt = 0; kt < K; kt += 64) {
    if (kt + 64 < K) {
      stage(kt + 64, buf ^ 1);
      wait_prefetch<6>();
    } else {
      asm volatile("s_waitcnt vmcnt(0)\n\ts_barrier" ::: "memory");
    }
    #pragma unroll
    for (int ks = 0; ks < 2; ++ks) {
      const int c = ks * 4 + quad;
      const int pc = (c ^ (ml & 7)) << 3;
      bf16x8 af[2], bfr[4];
      #pragma unroll
      for (int i = 0; i < 2; ++i)
        af[i] = *(const bf16x8*)&As[buf][wm + (i << 4) + ml][pc];
      #pragma unroll
      for (int j = 0; j < 2; ++j) {
        bfr[j]     = *(const bf16x8*)&Bs[buf][wn + (j << 4) + ml][pc];
        bfr[j + 2] = *(const bf16x8*)&Bs[buf][64 + wn + (j << 4) + ml][pc];
      }
      #pragma unroll
      for (int i = 0; i < 2; ++i)
        #pragma unroll
        for (int j = 0; j < 4; ++j)
          acc[i][j] = __builtin_amdgcn_mfma_f32_16x16x32_bf16(af[i], bfr[j], acc[i][j], 0, 0, 0);
    }
    asm volatile("s_barrier" ::: "memory");
    buf ^= 1;
  }

  float* out1 = out + (long)B_ * L_ * DM;
  const int rquad = quad << 2;
  #pragma unroll
  for (int i = 0; i < 2; ++i) {
    const long gm = bm + wm + (i << 4) + rquad;
    #pragma unroll
    for (int jj = 0; jj < 2; ++jj) {
      const long col = c0 + wn + (jj << 4) + ml;
      #pragma unroll
      for (int r = 0; r < 4; ++r) {
        float g = acc[i][jj][r];
        float h = acc[i][jj + 2][r];
        float e = (g / (1.f + expf(-g))) * h;
        long o = (gm + r) * DM + col;
        float f = xf[o];
        out[o]  = x0[o] + f + e;
        out1[o] = xd[o] + f + e;
      }
    }
  }
}

// ================= chunked SSD scan, conv+silu fused into staging =================
// Per (b,h,c): conv x/B/C slices from zx, then E=C.B^T, Y_intra=M.X (+D*x) -> yss,
// S^T -> Sbuf, unscaled C -> Cbuf (h==0 only; C is head-independent),
// exp(G_i) -> EGbuf (per-head), lam -> Lam. No cross-block sync.
__global__ __launch_bounds__(256) void ssd_chunk_kernel(
    const u16* __restrict__ zx, const float* __restrict__ dt_bias,
    const float* __restrict__ A_log, const float* __restrict__ cw,
    const float* __restrict__ cb, const float* __restrict__ Dp,
    u16* __restrict__ yss, float* __restrict__ Sbuf,
    u16* __restrict__ Cbuf, float* __restrict__ EGbuf,
    float* __restrict__ Lam) {
  const int c = blockIdx.x & 15;
  const int h = (blockIdx.x >> 4) & 31;
  const int b = blockIdx.x >> 9;
  const int bh = b * NH + h;
  const long zrow0 = (long)b * L_;
  const long crow = zrow0 + c * 64;
  const int tid = threadIdx.x, lane = tid & 63, wave = tid >> 6;

  __shared__ u16 Cs[64][72], Bs[64][72], Xt[64][72], Btw[64][72], Ms[64][72];
  __shared__ float Gs[64], wjL[64], dtL[64];

  if (wave == 0) {
    float draw = bf2f(zx[(crow + lane) * ZXS + (DI + CONVD) + h]) + dt_bias[h];
    float dt = (draw > 20.f) ? draw : log1pf(expf(draw));
    float g = -expf(A_log[h]) * dt;
    float G = g;
    #pragma unroll
    for (int off = 1; off < 64; off <<= 1) {
      float t = __shfl_up(G, off, 64);
      if (lane >= off) G += t;
    }
    float G63 = __shfl(G, 63, 64);
    Gs[lane] = G;
    wjL[lane] = expf(G63 - G) * dt;
    dtL[lane] = dt;
    EGbuf[(bh * 16 + c) * 64 + lane] = expf(G);   // per-head decay for ssd_final
    if (lane == 63) Lam[bh * 16 + c] = expf(G63);
  }
  __syncthreads();

  // --- staging with fused conv+silu (x:g0-15, B:g16-31, C:g32-47) ---
  for (int idx = tid; idx < 3072; idx += 256) {
    int r = idx / 48;
    int g = idx % 48;
    int t = c * 64 + r;
    long zcol;
    if (g < 16)      zcol = DI + (long)h * HD + (g << 2);
    else if (g < 32) zcol = DI + DI + ((g - 16) << 2);
    else             zcol = DI + DI + DSTATE + ((g - 32) << 2);
    int cc = (int)(zcol - DI);
    float4 acc = *(const float4*)(cb + cc);
    float4 wv0 = *(const float4*)(cw + (cc + 0) * 4);
    float4 wv1 = *(const float4*)(cw + (cc + 1) * 4);
    float4 wv2 = *(const float4*)(cw + (cc + 2) * 4);
    float4 wv3 = *(const float4*)(cw + (cc + 3) * 4);
    const float wt0[4] = {wv0.x, wv0.y, wv0.z, wv0.w};
    const float wt1[4] = {wv1.x, wv1.y, wv1.z, wv1.w};
    const float wt2[4] = {wv2.x, wv2.y, wv2.z, wv2.w};
    const float wt3[4] = {wv3.x, wv3.y, wv3.z, wv3.w};
    #pragma unroll
    for (int i = 0; i < 4; ++i) {
      int tau = t - 3 + i;
      if (tau >= 0) {
        ushort4 xb = *(const ushort4*)(zx + (zrow0 + tau) * ZXS + zcol);
        acc.x = fmaf(bf2f(xb.x), wt0[i], acc.x);
        acc.y = fmaf(bf2f(xb.y), wt1[i], acc.y);
        acc.z = fmaf(bf2f(xb.z), wt2[i], acc.z);
        acc.w = fmaf(bf2f(xb.w), wt3[i], acc.w);
      }
    }
    acc.x = acc.x / (1.f + expf(-acc.x));
    acc.y = acc.y / (1.f + expf(-acc.y));
    acc.z = acc.z / (1.f + expf(-acc.z));
    acc.w = acc.w / (1.f + expf(-acc.w));
    if (g < 16) {
      int k = g << 2;
      Xt[k + 0][r] = f2bf(acc.x); Xt[k + 1][r] = f2bf(acc.y);
      Xt[k + 2][r] = f2bf(acc.z); Xt[k + 3][r] = f2bf(acc.w);
    } else if (g < 32) {
      int n = (g - 16) << 2;
      *(ushort4*)&Bs[r][n] = make_ushort4(f2bf(acc.x), f2bf(acc.y), f2bf(acc.z), f2bf(acc.w));
      float w = wjL[r];
      Btw[n + 0][r] = f2bf(acc.x * w); Btw[n + 1][r] = f2bf(acc.y * w);
      Btw[n + 2][r] = f2bf(acc.z * w); Btw[n + 3][r] = f2bf(acc.w * w);
    } else {
      int n = (g - 32) << 2;
      ushort4 cv = make_ushort4(f2bf(acc.x), f2bf(acc.y), f2bf(acc.z), f2bf(acc.w));
      *(ushort4*)&Cs[r][n] = cv;
      if (h == 0)   // C is head-independent: write UNSCALED once
        *(ushort4*)(Cbuf + (crow + r) * 64 + n) = cv;
    }
  }
  __syncthreads();

  const int ml = lane & 15;
  const int mrow = wave * 16 + ml;
  const int quad = lane >> 4;
  // GEMM1: E = C.B^T
  f32x4 accE[4];
  #pragma unroll
  for (int j = 0; j < 4; ++j) accE[j] = (f32x4){0.f, 0.f, 0.f, 0.f};
  #pragma unroll
  for (int ks = 0; ks < 2; ++ks) {
    int k0 = ks * 32 + quad * 8;
    bf16x8 a = *(const bf16x8*)&Cs[mrow][k0];
    #pragma unroll
    for (int j = 0; j < 4; ++j) {
      bf16x8 bfr = *(const bf16x8*)&Bs[j * 16 + ml][k0];
      accE[j] = __builtin_amdgcn_mfma_f32_16x16x32_bf16(a, bfr, accE[j], 0, 0, 0);
    }
  }
  #pragma unroll
  for (int j = 0; j < 4; ++j) {
    int jc = j * 16 + ml;
    float Gj = Gs[jc], dtj = dtL[jc];
    #pragma unroll
    for (int r = 0; r < 4; ++r) {
      int ir = wave * 16 + quad * 4 + r;
      float v = (ir >= jc) ? accE[j][r] * expf(Gs[ir] - Gj) * dtj : 0.f;
      Ms[ir][jc] = f2bf(v);
    }
  }
  __syncthreads();
  // GEMM2: Y_intra = M.X ; GEMM3: S^T = X^T.(Bw)^T
  f32x4 accY[4], accS[4];
  #pragma unroll
  for (int j = 0; j < 4; ++j) { accY[j] = (f32x4){0.f,0.f,0.f,0.f}; accS[j] = (f32x4){0.f,0.f,0.f,0.f}; }
  #pragma unroll
  for (int ks = 0; ks < 2; ++ks) {
    int k0 = ks * 32 + quad * 8;
    bf16x8 aM = *(const bf16x8*)&Ms[mrow][k0];
    bf16x8 aX = *(const bf16x8*)&Xt[mrow][k0];
    #pragma unroll
    for (int j = 0; j < 4; ++j) {
      bf16x8 bX = *(const bf16x8*)&Xt[j * 16 + ml][k0];
      bf16x8 bB = *(const bf16x8*)&Btw[j * 16 + ml][k0];
      accY[j] = __builtin_amdgcn_mfma_f32_16x16x32_bf16(aM, bX, accY[j], 0, 0, 0);
      accS[j] = __builtin_amdgcn_mfma_f32_16x16x32_bf16(aX, bB, accS[j], 0, 0, 0);
    }
  }
  // write Y_intra + D*x, and S^T
  const float Dh = Dp[h];
  float* Sc = Sbuf + (long)(bh * 16 + c) * 4096;
  #pragma unroll
  for (int j = 0; j < 4; ++j) {
    int p = j * 16 + ml;
    #pragma unroll
    for (int r = 0; r < 4; ++r) {
      int ir = wave * 16 + quad * 4 + r;
      float y = accY[j][r] + Dh * bf2f(Xt[p][ir]);
      yss[(crow + ir) * DI + (long)h * HD + p] = f2bf(y);
      Sc[ir * 64 + p] = accS[j][r];   // for accS: ir = state-row p, p = state-col n
    }
  }
}

// S2: parallel serial-combine; Sbuf[c] becomes carry-in H for chunk c
__global__ __launch_bounds__(256) void ssd_combine_kernel(
    float* __restrict__ Sbuf, const float* __restrict__ Lam) {
  const int bh = blockIdx.x >> 4;
  const int e = (blockIdx.x & 15) * 256 + threadIdx.x;
  float* base = Sbuf + (long)bh * 16 * 4096 + e;
  const float* lamp = Lam + bh * 16;
  float H = 0.f;
  for (int cc = 0; cc < 16; ++cc) {
    float lam = lamp[cc];
    float v = base[cc * 4096];
    base[cc * 4096] = H;
    H = fmaf(lam, H, v);
  }
}

// S3: yss += (C * exp(G_i)) . Hin^T  (C from Cbuf, eg from EGbuf, Hin from Sbuf)
__global__ __launch_bounds__(256) void ssd_final_kernel(
    const u16* __restrict__ Cbuf, const float* __restrict__ Sbuf,
    const float* __restrict__ EGbuf, u16* __restrict__ yss) {
  const int c = blockIdx.x & 15;
  const int h = (blockIdx.x >> 4) & 31;
  const int b = blockIdx.x >> 9;
  const int bh = b * NH + h;
  const long crow = (long)b * L_ + c * 64;
  const int tid = threadIdx.x, lane = tid & 63, wave = tid >> 6;
  __shared__ u16 Csc[64][72], Hs[64][72];
  __shared__ float egL[64];
  if (tid < 64) egL[tid] = EGbuf[(bh * 16 + c) * 64 + tid];
  __syncthreads();
  const float* Sc = Sbuf + (long)(bh * 16 + c) * 4096;
  for (int idx = tid; idx < 1024; idx += 256) {
    int r = idx >> 4, c4 = (idx & 15) << 2;
    float4 hv = *(const float4*)(Sc + r * 64 + c4);
    *(ushort4*)&Hs[r][c4] = make_ushort4(f2bf(hv.x), f2bf(hv.y), f2bf(hv.z), f2bf(hv.w));
    float eg = egL[r];
    ushort4 cv = *(const ushort4*)(Cbuf + (crow + r) * 64 + c4);
    *(ushort4*)&Csc[r][c4] = make_ushort4(f2bf(bf2f(cv.x) * eg), f2bf(bf2f(cv.y) * eg),
                                          f2bf(bf2f(cv.z) * eg), f2bf(bf2f(cv.w) * eg));
  }
  __syncthreads();
  const int ml = lane & 15;
  const int mrow = wave * 16 + ml;
  const int quad = lane >> 4;
  f32x4 acc[4];
  #pragma unroll
  for (int j = 0; j < 4; ++j) acc[j] = (f32x4){0.f, 0.f, 0.f, 0.f};
  #pragma unroll
  for (int ks = 0; ks < 2; ++ks) {
    int k0 = ks * 32 + quad * 8;
    bf16x8 a = *(const bf16x8*)&Csc[mrow][k0];
    #pragma unroll
    for (int j = 0; j < 4; ++j) {
      bf16x8 bfr = *(const bf16x8*)&Hs[j * 16 + ml][k0];
      acc[j] = __builtin_amdgcn_mfma_f32_16x16x32_bf16(a, bfr, acc[j], 0, 0, 0);
    }
  }
  #pragma unroll
  for (int j = 0; j < 4; ++j) {
    int p = j * 16 + ml;
    #pragma unroll
    for (int r = 0; r < 4; ++r) {
      int ir = wave * 16 + quad * 4 + r;
      long o = (crow + ir) * DI + (long)h * HD + p;
      yss[o] = f2bf(bf2f(yss[o]) + acc[j][r]);
    }
  }
}

// ---------------- gated rmsnorm (bf16 y,z) + zero xf for split-K atomics ----------------
__global__ __launch_bounds__(256) void gated_rms_kernel(
    const u16* __restrict__ y, const u16* __restrict__ zx,
    const float* __restrict__ wt, u16* __restrict__ out,
    float* __restrict__ xf_zero) {
  const int row = blockIdx.x;
  const int c = threadIdx.x << 3;
  const u16* yr = y + (long)row * DI + c;
  const u16* zr = zx + (long)row * ZXS + c;
  *(float4*)(xf_zero + (long)row * DM + (threadIdx.x << 2)) = make_float4(0.f, 0.f, 0.f, 0.f);
  float v[8];
  float ss = 0.f;
  #pragma unroll
  for (int i = 0; i < 8; i += 4) {
    ushort4 y4 = *(const ushort4*)(yr + i);
    ushort4 z4 = *(const ushort4*)(zr + i);
    const float zz[4] = {bf2f(z4.x), bf2f(z4.y), bf2f(z4.z), bf2f(z4.w)};
    const float yy[4] = {bf2f(y4.x), bf2f(y4.y), bf2f(y4.z), bf2f(y4.w)};
    #pragma unroll
    for (int j = 0; j < 4; ++j) {
      float sg = zz[j] / (1.f + expf(-zz[j]));
      float val = yy[j] * sg;
      v[i + j] = val;
      ss += val * val;
    }
  }
  float tot = block_reduce_sum256(ss);
  float sc = rsqrtf(tot * (1.0f / DI) + 1e-5f);
  const float* wr = wt + c;
  *(ushort4*)(out + (long)row * DI + c) =
      make_ushort4(f2bf(v[0] * sc * wr[0]), f2bf(v[1] * sc * wr[1]),
                   f2bf(v[2] * sc * wr[2]), f2bf(v[3] * sc * wr[3]));
  *(ushort4*)(out + (long)row * DI + c + 4) =
      make_ushort4(f2bf(v[4] * sc * wr[4]), f2bf(v[5] * sc * wr[5]),
                   f2bf(v[6] * sc * wr[6]), f2bf(v[7] * sc * wr[7]));
}

extern "C" void kernel_launch(void* const* d_in, const int* in_sizes, int n_in,
                              void* d_out, int out_size, void* d_ws, size_t ws_size,
                              hipStream_t stream) {
  const float* x        = (const float*)d_in[0];
  const float* x_d      = (const float*)d_in[1];
  const float* norm_w   = (const float*)d_in[2];
  const float* W_in     = (const float*)d_in[3];
  const float* conv_w   = (const float*)d_in[4];
  const float* conv_b   = (const float*)d_in[5];
  const float* dt_bias  = (const float*)d_in[6];
  const float* A_log    = (const float*)d_in[7];
  const float* D_param  = (const float*)d_in[8];
  const float* ssm_w    = (const float*)d_in[9];
  const float* W_out    = (const float*)d_in[10];
  const float* w1       = (const float*)d_in[11];
  const float* w2       = (const float*)d_in[12];
  float* out = (float*)d_out;

  char* wsc = (char*)d_ws;
  size_t off = 0;
  auto alloc = [&](size_t n) { char* p = wsc + off; off += (n + 255) & ~(size_t)255; return p; };
  u16*   zx   = (u16*)alloc((size_t)2048 * ZXS * 2);
  u16*   yss  = (u16*)alloc((size_t)2048 * 2048 * 2);
  float* xf   = (float*)alloc((size_t)2048 * 1024 * 4);
  float* Sbuf = (float*)alloc((size_t)64 * 16 * 4096 * 4);
  u16*   Cbuf = (u16*)alloc((size_t)2048 * 64 * 2);
  float* EGbuf= (float*)alloc((size_t)65536 * 4);
  float* Lam  = (float*)alloc((size_t)1024 * 4);
  u16* xlnb   = (u16*)alloc((size_t)2048 * 1024 * 2);
  u16* ygnb   = (u16*)alloc((size_t)2048 * 2048 * 2);
  u16* xln2b  = (u16*)alloc((size_t)2048 * 1024 * 2);
  u16* Winb   = (u16*)alloc((size_t)4256 * 1024 * 2);
  u16* Woutb  = (u16*)alloc((size_t)1024 * 2048 * 2);
  u16* w12b   = (u16*)alloc((size_t)2048 * 1024 * 2);

  // 0+1) rmsnorm(x) + all weight conversions, one launch
  rms_and_convert<<<2048 + 8352, 256, 0, stream>>>(x, norm_w, xlnb,
      W_in, W_out, w1, w2, Winb, Woutb, w12b);
  // 2) in-proj -> bf16 zx (padded stride)
  gemm_lds<4, 2, 1><<<dim3(68, 16), 256, 0, stream>>>(xlnb, Winb, zx, ZXS, 4256, 1024, 1024);
  // 3) chunked SSD with fused conv+silu (no cross-block sync)
  ssd_chunk_kernel<<<1024, 256, 0, stream>>>(zx, dt_bias, A_log, conv_w, conv_b,
                                             D_param, yss, Sbuf, Cbuf, EGbuf, Lam);
  ssd_combine_kernel<<<1024, 256, 0, stream>>>(Sbuf, Lam);
  ssd_final_kernel<<<1024, 256, 0, stream>>>(Cbuf, Sbuf, EGbuf, yss);
  // 4) gated rmsnorm -> bf16 (+ zeroes xf for split-K)
  gated_rms_kernel<<<2048, 256, 0, stream>>>(yss, zx, ssm_w, ygnb, xf);
  // 5) out-proj: split-K=2, atomicAdd into xf
  gemm_lds<2, 2, 2><<<dim3(16, 32, 2), 256, 0, stream>>>(ygnb, Woutb, xf, 1024, 1024, 1024, 2048);
  // 6) rmsnorm(x + xf) -> bf16
  add_rms_kernel<<<2048, 256, 0, stream>>>(x, xf, norm_w, xln2b, 1e-6f);
  // 7) fused MLP GEMM + gate + final outputs
  gemm_mlp_final<<<dim3(16, 32), 256, 0, stream>>>(xln2b, w12b, x, x_d, xf, out, 1024);
}